// Round 13
// baseline (148.382 us; speedup 1.0000x reference)
//
#include <hip/hip_runtime.h>
#include <hip/hip_bf16.h>

#define N_NODES 10000
#define N_EDGES 640000
#define FEATS   128
#define CAP     192    // ELL slots/node; degree ~ Poisson(64), P(>192) ~ 0
#define NBUCK   157    // buckets of 64 dst-nodes
#define ECHUNK  2048   // edges per phase-1 block (private region size)
#define NPB     313    // phase-1 blocks = ceil(640000/2048)
#define OSTR    160    // goffs row stride (ushorts)
#define TILE    8      // nodes per fused block (1 per wave)

__device__ __forceinline__ float bflo(uint p) { return __uint_as_float(p << 16); }
__device__ __forceinline__ float bfhi(uint p) { return __uint_as_float(p & 0xffff0000u); }

// ---- phase 1: per-block private bucket-sort; ALL writes streaming ---------
// (+ grid-stride f32->bf16 feature conversion tail)

__global__ __launch_bounds__(256) void bin_pack(const int* __restrict__ src,
                                                const int* __restrict__ dst,
                                                uint* __restrict__ bucketed,
                                                ushort* __restrict__ goffs,
                                                const float* __restrict__ features,
                                                ushort* __restrict__ hb0) {
    __shared__ int hist[NBUCK];
    __shared__ int offs[NBUCK + 1];
    __shared__ int scan[256];
    __shared__ uint staging[ECHUNK];  // 8 KB
    const int tid = threadIdx.x;
    const int b = blockIdx.x;
    const int e0 = b * ECHUNK;
    for (int i = tid; i < NBUCK; i += 256) hist[i] = 0;
    __syncthreads();
    int dreg[8];
#pragma unroll
    for (int i = 0; i < 8; ++i) {
        int e = e0 + tid + i * 256;
        dreg[i] = (e < N_EDGES) ? __builtin_nontemporal_load(dst + e) : -1;
        if (dreg[i] >= 0) atomicAdd(&hist[dreg[i] >> 6], 1);
    }
    __syncthreads();
    int val = (tid < NBUCK) ? hist[tid] : 0;
    scan[tid] = val;
    __syncthreads();
    for (int off = 1; off < 256; off <<= 1) {
        int t = (tid >= off) ? scan[tid - off] : 0;
        __syncthreads();
        scan[tid] += t;
        __syncthreads();
    }
    if (tid < NBUCK) offs[tid] = scan[tid] - val;   // exclusive
    if (tid == 0) offs[NBUCK] = scan[NBUCK - 1];    // total real edges
    for (int i = tid; i < NBUCK; i += 256) hist[i] = 0;
    __syncthreads();
    if (tid <= NBUCK) goffs[b * OSTR + tid] = (ushort)offs[tid];
#pragma unroll
    for (int i = 0; i < 8; ++i) {
        int e = e0 + tid + i * 256;
        if (dreg[i] >= 0) {
            int s = __builtin_nontemporal_load(src + e);
            int bk = dreg[i] >> 6;
            int slot = offs[bk] + atomicAdd(&hist[bk], 1);
            staging[slot] = ((uint)s << 6) | (uint)(dreg[i] & 63);
        }
    }
    __syncthreads();
    uint4* gu = (uint4*)(bucketed + (size_t)b * ECHUNK);
    const uint4* lu = (const uint4*)staging;
#pragma unroll
    for (int i = 0; i < ECHUNK / 4 / 256; ++i)
        gu[tid + i * 256] = lu[tid + i * 256];

    // ---- f2b tail: features f32 -> bf16 table (grid-stride) ----
    const int n4 = N_NODES * FEATS / 4;
    for (int i = b * 256 + tid; i < n4; i += NPB * 256) {
        const float* fp = features + (size_t)i * 4;
        float f0 = __builtin_nontemporal_load(fp + 0);
        float f1 = __builtin_nontemporal_load(fp + 1);
        float f2 = __builtin_nontemporal_load(fp + 2);
        float f3 = __builtin_nontemporal_load(fp + 3);
        __hip_bfloat16 b0 = __float2bfloat16(f0);
        __hip_bfloat16 b1 = __float2bfloat16(f1);
        __hip_bfloat16 b2 = __float2bfloat16(f2);
        __hip_bfloat16 b3 = __float2bfloat16(f3);
        ushort4 o;
        o.x = *(const ushort*)&b0; o.y = *(const ushort*)&b1;
        o.z = *(const ushort*)&b2; o.w = *(const ushort*)&b3;
        ((ushort4*)hb0)[i] = o;
    }
}

// ---- phase 2: per-bucket ELL in LDS; 256 INDEPENDENT span-walkers ---------
// (thread-per-span = high TLP; spans are ~13 sequential-address loads each,
// pipelined across 256 concurrent walkers. Wave-coop variant regressed.)

__global__ __launch_bounds__(256) void build_ell(const uint* __restrict__ bucketed,
                                                 const ushort* __restrict__ goffs,
                                                 ushort* __restrict__ ell,
                                                 int* __restrict__ cnts) {
    __shared__ ushort lell[64 * CAP];  // 24 KB
    __shared__ int lcur[64];
    const int tid = threadIdx.x;
    const int bk = blockIdx.x;
    if (tid < 64) lcur[tid] = 0;
    __syncthreads();
    for (int b = tid; b < NPB; b += 256) {
        int off0 = goffs[b * OSTR + bk];
        int off1 = goffs[b * OSTR + bk + 1];
        const uint* p0 = bucketed + (size_t)b * ECHUNK;
        for (int i = off0; i < off1; ++i) {
            uint p = __builtin_nontemporal_load(p0 + i);
            int v = p & 63;
            int slot = atomicAdd(&lcur[v], 1);
            if (slot < CAP) lell[v * CAP + slot] = (ushort)(p >> 6);
        }
    }
    __syncthreads();
    const int node0 = bk * 64;
    int nn = N_NODES - node0;
    if (nn > 64) nn = 64;
    const uint4* lu = (const uint4*)lell;
    uint4* gu = (uint4*)(ell + (size_t)node0 * CAP);
    const int nq = nn * (CAP / 8);
    for (int i = tid; i < nq; i += 256) gu[i] = lu[i];
    for (int v = tid; v < nn; v += 256) {
        int c = lcur[v];
        cnts[node0 + v] = (c > CAP) ? CAP : c;
    }
}

// ---------------- fused hidden layer: z = h[v]+sum h[u]; out = z@W+b -------
// 512 threads = 8 waves, ONE NODE PER WAVE (max TLP: 10000 waves chip-wide).
// Streaming accesses (ELL indices, cnts) are non-temporal (scalar NT loads —
// the builtin rejects HIP vector types) so the bf16 h table keeps L2
// residency; h gathers stay normal priority.

__global__ __launch_bounds__(512) void fused_kernel(const ushort* __restrict__ hb,
                                                    const float* __restrict__ W,
                                                    const float* __restrict__ bias,
                                                    const int* __restrict__ cnts,
                                                    const ushort* __restrict__ ell,
                                                    ushort* __restrict__ hb_out) {
    __shared__ float sZ[TILE][132];
    const int tile0 = blockIdx.x * TILE;
    const int tid = threadIdx.x;
    const int lane = tid & 63;
    const int wv = tid >> 6;   // 0..7: one node per wave
    const int g = lane >> 4;   // edge group (4 edges/iter)
    const int q = lane & 15;   // 16B chunk within 256B row
    const uint4* __restrict__ hbq = (const uint4*)hb;

    const int v = tile0 + wv;
    int cnt = __builtin_nontemporal_load(cnts + v);
    if (cnt > CAP) cnt = CAP;
    const uint* __restrict__ row32 = (const uint*)(ell + (size_t)v * CAP);
    float acc[8];
#pragma unroll
    for (int i = 0; i < 8; ++i) acc[i] = 0.f;
#pragma unroll 2
    for (int j = 0; j < cnt; j += 4) {
        uint w0 = __builtin_nontemporal_load(row32 + (j >> 1));      // idx pair 0,1
        uint w1 = __builtin_nontemporal_load(row32 + (j >> 1) + 1);  // idx pair 2,3
        uint word = (g & 2) ? w1 : w0;
        uint u = (g & 1) ? (word >> 16) : (word & 0xffffu);
        float scale = (j + g < cnt) ? 1.0f : 0.0f;
        if (u > N_NODES - 1) u = N_NODES - 1;  // clamp garbage tail index
        uint4 p = hbq[u * 16 + q];
        acc[0] = fmaf(bflo(p.x), scale, acc[0]);
        acc[1] = fmaf(bfhi(p.x), scale, acc[1]);
        acc[2] = fmaf(bflo(p.y), scale, acc[2]);
        acc[3] = fmaf(bfhi(p.y), scale, acc[3]);
        acc[4] = fmaf(bflo(p.z), scale, acc[4]);
        acc[5] = fmaf(bfhi(p.z), scale, acc[5]);
        acc[6] = fmaf(bflo(p.w), scale, acc[6]);
        acc[7] = fmaf(bfhi(p.w), scale, acc[7]);
    }
#pragma unroll
    for (int d = 16; d < 64; d <<= 1) {
#pragma unroll
        for (int i = 0; i < 8; ++i) acc[i] += __shfl_xor(acc[i], d);
    }
    if (g == 0) {
        uint4 p = hbq[(size_t)v * 16 + q];     // self term (bf16 row)
        acc[0] += bflo(p.x); acc[1] += bfhi(p.x);
        acc[2] += bflo(p.y); acc[3] += bfhi(p.y);
        acc[4] += bflo(p.z); acc[5] += bfhi(p.z);
        acc[6] += bflo(p.w); acc[7] += bfhi(p.w);
        float4 a0 = {acc[0], acc[1], acc[2], acc[3]};
        float4 a1 = {acc[4], acc[5], acc[6], acc[7]};
        *(float4*)&sZ[wv][q * 8]     = a0;
        *(float4*)&sZ[wv][q * 8 + 4] = a1;
    }
    __syncthreads();

    // ---- GEMM phase: 512 threads, col = tid&127, 4 groups x 2 rows ----
    const int col = tid & 127;
    const int gg  = tid >> 7;   // 0..3
    float acc2[2] = {0.f, 0.f};
#pragma unroll 2
    for (int k = 0; k < 128; k += 4) {
        float w0 = W[(k + 0) * 128 + col];
        float w1 = W[(k + 1) * 128 + col];
        float w2 = W[(k + 2) * 128 + col];
        float w3 = W[(k + 3) * 128 + col];
#pragma unroll
        for (int r = 0; r < 2; ++r) {
            float4 z = *(const float4*)&sZ[gg * 2 + r][k];  // broadcast
            acc2[r] = fmaf(z.x, w0, acc2[r]);
            acc2[r] = fmaf(z.y, w1, acc2[r]);
            acc2[r] = fmaf(z.z, w2, acc2[r]);
            acc2[r] = fmaf(z.w, w3, acc2[r]);
        }
    }
    const float b = bias[col];
#pragma unroll
    for (int r = 0; r < 2; ++r) {
        const int vv = tile0 + gg * 2 + r;
        float y = fmaxf(acc2[r] + b, 0.f);
        __hip_bfloat16 bv = __float2bfloat16(y);
        hb_out[(size_t)vv * FEATS + col] = *(const ushort*)&bv;
    }
}

// ---------------- layer 4a: y = h @ W2 (128->64), bf16 out, no bias --------

__global__ __launch_bounds__(256) void gemm64(const ushort* __restrict__ hb,
                                              const float* __restrict__ W,
                                              ushort* __restrict__ yb) {
    __shared__ float sZ[16][132];
    const int node0 = blockIdx.x * 16;
    const int tid = threadIdx.x;
    const uint* hrow = (const uint*)(hb + (size_t)node0 * 128);
    for (int i = tid; i < 16 * 64; i += 256) {   // 1024 uints = 16 rows x 128 bf16
        uint p = hrow[i];
        int row = i >> 6, c2 = (i & 63) * 2;
        sZ[row][c2] = bflo(p);
        sZ[row][c2 + 1] = bfhi(p);
    }
    __syncthreads();
    const int col = tid & 63;
    const int g = tid >> 6;   // 4 groups x 4 rows
    float acc[4] = {0.f, 0.f, 0.f, 0.f};
#pragma unroll 2
    for (int k = 0; k < 128; k += 4) {
        float w0 = W[(k + 0) * 64 + col];
        float w1 = W[(k + 1) * 64 + col];
        float w2 = W[(k + 2) * 64 + col];
        float w3 = W[(k + 3) * 64 + col];
#pragma unroll
        for (int r = 0; r < 4; ++r) {
            float4 z = *(const float4*)&sZ[g * 4 + r][k];  // broadcast
            acc[r] = fmaf(z.x, w0, acc[r]);
            acc[r] = fmaf(z.y, w1, acc[r]);
            acc[r] = fmaf(z.z, w2, acc[r]);
            acc[r] = fmaf(z.w, w3, acc[r]);
        }
    }
#pragma unroll
    for (int r = 0; r < 4; ++r) {
        __hip_bfloat16 bv = __float2bfloat16(acc[r]);
        yb[(size_t)(node0 + g * 4 + r) * 64 + col] = *(const ushort*)&bv;
    }
}

// ---------------- layer 4b: out[v] = y[v] + sum_u y[u] + b2 (64-wide) ------

__global__ __launch_bounds__(256) void agg64(const ushort* __restrict__ yb,
                                             const int* __restrict__ cnts,
                                             const ushort* __restrict__ ell,
                                             const float* __restrict__ bias,
                                             float* __restrict__ out) {
    const int v = blockIdx.x * 4 + (threadIdx.x >> 6);
    const int lane = threadIdx.x & 63;
    const int g = lane >> 3;   // 8 edge groups per iter
    const int q = lane & 7;    // 16B chunk within 128B row
    int cnt = __builtin_nontemporal_load(cnts + v);
    if (cnt > CAP) cnt = CAP;
    const uint* __restrict__ row32 = (const uint*)(ell + (size_t)v * CAP);
    const uint4* __restrict__ ybq = (const uint4*)yb;
    float acc[8];
#pragma unroll
    for (int i = 0; i < 8; ++i) acc[i] = 0.f;
#pragma unroll 2
    for (int j = 0; j < cnt; j += 8) {
        uint wa = __builtin_nontemporal_load(row32 + (j >> 1) + 0);
        uint wb = __builtin_nontemporal_load(row32 + (j >> 1) + 1);
        uint wc = __builtin_nontemporal_load(row32 + (j >> 1) + 2);
        uint wd = __builtin_nontemporal_load(row32 + (j >> 1) + 3);
        uint a = (g & 2) ? wb : wa;
        uint b = (g & 2) ? wd : wc;
        uint word = (g & 4) ? b : a;
        uint u = (g & 1) ? (word >> 16) : (word & 0xffffu);
        float scale = (j + g < cnt) ? 1.0f : 0.0f;
        if (u > N_NODES - 1) u = N_NODES - 1;
        uint4 p = ybq[u * 8 + q];
        acc[0] = fmaf(bflo(p.x), scale, acc[0]);
        acc[1] = fmaf(bfhi(p.x), scale, acc[1]);
        acc[2] = fmaf(bflo(p.y), scale, acc[2]);
        acc[3] = fmaf(bfhi(p.y), scale, acc[3]);
        acc[4] = fmaf(bflo(p.z), scale, acc[4]);
        acc[5] = fmaf(bfhi(p.z), scale, acc[5]);
        acc[6] = fmaf(bflo(p.w), scale, acc[6]);
        acc[7] = fmaf(bfhi(p.w), scale, acc[7]);
    }
#pragma unroll
    for (int d = 8; d < 64; d <<= 1) {
#pragma unroll
        for (int i = 0; i < 8; ++i) acc[i] += __shfl_xor(acc[i], d);
    }
    if (g == 0) {
        uint4 p = ybq[(size_t)v * 8 + q];   // self term y[v] (bf16)
        const float4* br = (const float4*)bias;
        float4 b0 = br[q * 2], b1 = br[q * 2 + 1];
        float4 o0, o1;
        o0.x = acc[0] + bflo(p.x) + b0.x; o0.y = acc[1] + bfhi(p.x) + b0.y;
        o0.z = acc[2] + bflo(p.y) + b0.z; o0.w = acc[3] + bfhi(p.y) + b0.w;
        o1.x = acc[4] + bflo(p.z) + b1.x; o1.y = acc[5] + bfhi(p.z) + b1.y;
        o1.z = acc[6] + bflo(p.w) + b1.z; o1.w = acc[7] + bfhi(p.w) + b1.w;
        float4* outr = (float4*)(out + (size_t)v * 64);
        outr[q * 2]     = o0;
        outr[q * 2 + 1] = o1;
    }
}

// ---------------- launch ----------------

extern "C" void kernel_launch(void* const* d_in, const int* in_sizes, int n_in,
                              void* d_out, int out_size, void* d_ws, size_t ws_size,
                              hipStream_t stream) {
    const float* features = (const float*)d_in[0];
    const int*   src      = (const int*)d_in[1];
    const int*   dst      = (const int*)d_in[2];
    const float* W1 = (const float*)d_in[3];
    const float* b1 = (const float*)d_in[4];
    const float* W3 = (const float*)d_in[5];
    const float* b3 = (const float*)d_in[6];
    const float* W4 = (const float*)d_in[7];
    const float* b4 = (const float*)d_in[8];
    const float* W2 = (const float*)d_in[9];
    const float* b2 = (const float*)d_in[10];
    float* out = (float*)d_out;

    int*    cnts     = (int*)d_ws;                         // 10240 ints
    ushort* goffs    = (ushort*)(cnts + 10240);            // NPB*OSTR ushorts
    uint*   bucketed = (uint*)(goffs + 50240);             // NPB*ECHUNK uints (2.56 MB)
    ushort* ell      = (ushort*)(bucketed + (size_t)NPB * ECHUNK); // 3.84 MB
    ushort* hb0      = ell + (size_t)N_NODES * CAP;        // 10000*128 bf16
    ushort* hb1      = hb0 + (size_t)N_NODES * FEATS;      // 10000*128 bf16
    ushort* yb64     = hb1 + (size_t)N_NODES * FEATS;      // 10000*64 bf16

    bin_pack<<<NPB, 256, 0, stream>>>(src, dst, bucketed, goffs, features, hb0);
    build_ell<<<NBUCK, 256, 0, stream>>>(bucketed, goffs, ell, cnts);

    const int fblocks = N_NODES / TILE;  // 1250

    fused_kernel<<<fblocks, 512, 0, stream>>>(hb0, W1, b1, cnts, ell, hb1);
    fused_kernel<<<fblocks, 512, 0, stream>>>(hb1, W3, b3, cnts, ell, hb0);
    fused_kernel<<<fblocks, 512, 0, stream>>>(hb0, W4, b4, cnts, ell, hb1);
    // Layer 4: y = h3@W2 (64-wide), then out = y[v] + sum y[u] + b2
    gemm64<<<N_NODES / 16, 256, 0, stream>>>(hb1, W2, yb64);
    agg64<<<N_NODES / 4, 256, 0, stream>>>(yb64, cnts, ell, b2, out);
}

// Round 14
// 124.035 us; speedup vs baseline: 1.1963x; 1.1963x over previous
//
#include <hip/hip_runtime.h>
#include <hip/hip_bf16.h>

#define N_NODES 10000
#define N_EDGES 640000
#define FEATS   128
#define CAP     192    // ELL slots/node; degree ~ Poisson(64), P(>192) ~ 0
#define NBUCK   157    // buckets of 64 dst-nodes
#define ECHUNK  2048   // edges per phase-1 block (private region size)
#define NPB     313    // phase-1 blocks = ceil(640000/2048)
#define OSTR    160    // goffs row stride (ushorts)
#define TILE    16     // nodes per fused block (8 waves x 2 nodes)

__device__ __forceinline__ float bflo(uint p) { return __uint_as_float(p << 16); }
__device__ __forceinline__ float bfhi(uint p) { return __uint_as_float(p & 0xffff0000u); }

// ---- phase 1: per-block private bucket-sort; ALL writes streaming ---------
// (+ grid-stride f32->bf16 feature conversion tail). NO nontemporal loads:
// NT on the index/pointer-chase path regressed 25% (R13 post-mortem).

__global__ __launch_bounds__(256) void bin_pack(const int* __restrict__ src,
                                                const int* __restrict__ dst,
                                                uint* __restrict__ bucketed,
                                                ushort* __restrict__ goffs,
                                                const float* __restrict__ features,
                                                ushort* __restrict__ hb0) {
    __shared__ int hist[NBUCK];
    __shared__ int offs[NBUCK + 1];
    __shared__ int scan[256];
    __shared__ uint staging[ECHUNK];  // 8 KB
    const int tid = threadIdx.x;
    const int b = blockIdx.x;
    const int e0 = b * ECHUNK;
    for (int i = tid; i < NBUCK; i += 256) hist[i] = 0;
    __syncthreads();
    int dreg[8];
#pragma unroll
    for (int i = 0; i < 8; ++i) {
        int e = e0 + tid + i * 256;
        dreg[i] = (e < N_EDGES) ? dst[e] : -1;
        if (dreg[i] >= 0) atomicAdd(&hist[dreg[i] >> 6], 1);
    }
    __syncthreads();
    int val = (tid < NBUCK) ? hist[tid] : 0;
    scan[tid] = val;
    __syncthreads();
    for (int off = 1; off < 256; off <<= 1) {
        int t = (tid >= off) ? scan[tid - off] : 0;
        __syncthreads();
        scan[tid] += t;
        __syncthreads();
    }
    if (tid < NBUCK) offs[tid] = scan[tid] - val;   // exclusive
    if (tid == 0) offs[NBUCK] = scan[NBUCK - 1];    // total real edges
    for (int i = tid; i < NBUCK; i += 256) hist[i] = 0;
    __syncthreads();
    if (tid <= NBUCK) goffs[b * OSTR + tid] = (ushort)offs[tid];
#pragma unroll
    for (int i = 0; i < 8; ++i) {
        int e = e0 + tid + i * 256;
        if (dreg[i] >= 0) {
            int s = src[e];
            int bk = dreg[i] >> 6;
            int slot = offs[bk] + atomicAdd(&hist[bk], 1);
            staging[slot] = ((uint)s << 6) | (uint)(dreg[i] & 63);
        }
    }
    __syncthreads();
    uint4* gu = (uint4*)(bucketed + (size_t)b * ECHUNK);
    const uint4* lu = (const uint4*)staging;
#pragma unroll
    for (int i = 0; i < ECHUNK / 4 / 256; ++i)
        gu[tid + i * 256] = lu[tid + i * 256];

    // ---- f2b tail: features f32 -> bf16 table (grid-stride) ----
    const int n4 = N_NODES * FEATS / 4;
    for (int i = b * 256 + tid; i < n4; i += NPB * 256) {
        float4 f = ((const float4*)features)[i];
        __hip_bfloat16 b0 = __float2bfloat16(f.x);
        __hip_bfloat16 b1 = __float2bfloat16(f.y);
        __hip_bfloat16 b2 = __float2bfloat16(f.z);
        __hip_bfloat16 b3 = __float2bfloat16(f.w);
        ushort4 o;
        o.x = *(const ushort*)&b0; o.y = *(const ushort*)&b1;
        o.z = *(const ushort*)&b2; o.w = *(const ushort*)&b3;
        ((ushort4*)hb0)[i] = o;
    }
}

// ---- phase 2: per-bucket ELL in LDS; 256 INDEPENDENT span-walkers ---------

__global__ __launch_bounds__(256) void build_ell(const uint* __restrict__ bucketed,
                                                 const ushort* __restrict__ goffs,
                                                 ushort* __restrict__ ell,
                                                 int* __restrict__ cnts) {
    __shared__ ushort lell[64 * CAP];  // 24 KB
    __shared__ int lcur[64];
    const int tid = threadIdx.x;
    const int bk = blockIdx.x;
    if (tid < 64) lcur[tid] = 0;
    __syncthreads();
    for (int b = tid; b < NPB; b += 256) {
        int off0 = goffs[b * OSTR + bk];
        int off1 = goffs[b * OSTR + bk + 1];
        const uint* p0 = bucketed + (size_t)b * ECHUNK;
        for (int i = off0; i < off1; ++i) {
            uint p = p0[i];
            int v = p & 63;
            int slot = atomicAdd(&lcur[v], 1);
            if (slot < CAP) lell[v * CAP + slot] = (ushort)(p >> 6);
        }
    }
    __syncthreads();
    const int node0 = bk * 64;
    int nn = N_NODES - node0;
    if (nn > 64) nn = 64;
    const uint4* lu = (const uint4*)lell;
    uint4* gu = (uint4*)(ell + (size_t)node0 * CAP);
    const int nq = nn * (CAP / 8);
    for (int i = tid; i < nq; i += 256) gu[i] = lu[i];
    for (int v = tid; v < nn; v += 256) {
        int c = lcur[v];
        cnts[node0 + v] = (c > CAP) ? CAP : c;
    }
}

// ---------------- fused hidden layer: z = h[v]+sum h[u]; out = z@W+b -------
// TILE=16, 512 threads = 8 waves x 2 nodes (same wave structure & chip TLP
// as the 118.7us baseline), but W streamed once per 16 rows instead of 8:
// W L2-request traffic halved (80->40 MB/layer), half the blocks.

__global__ __launch_bounds__(512) void fused_kernel(const ushort* __restrict__ hb,
                                                    const float* __restrict__ W,
                                                    const float* __restrict__ bias,
                                                    const int* __restrict__ cnts,
                                                    const ushort* __restrict__ ell,
                                                    ushort* __restrict__ hb_out) {
    __shared__ float sZ[TILE][132];
    const int tile0 = blockIdx.x * TILE;
    const int tid = threadIdx.x;
    const int lane = tid & 63;
    const int wv = tid >> 6;   // 0..7
    const int g = lane >> 4;   // edge group (4 edges/iter)
    const int q = lane & 15;   // 16B chunk within 256B row
    const uint4* __restrict__ hbq = (const uint4*)hb;

#pragma unroll
    for (int n = 0; n < 2; ++n) {
        const int v = tile0 + wv * 2 + n;
        int cnt = cnts[v];
        if (cnt > CAP) cnt = CAP;
        const ushort* __restrict__ row = ell + (size_t)v * CAP;
        float acc[8];
#pragma unroll
        for (int i = 0; i < 8; ++i) acc[i] = 0.f;
#pragma unroll 2
        for (int j = 0; j < cnt; j += 4) {
            uint2 iv = *(const uint2*)(row + j);   // broadcast index load (L1-hot)
            uint word = (g & 2) ? iv.y : iv.x;
            uint u = (g & 1) ? (word >> 16) : (word & 0xffffu);
            float scale = (j + g < cnt) ? 1.0f : 0.0f;
            if (u > N_NODES - 1) u = N_NODES - 1;  // clamp garbage tail index
            uint4 p = hbq[u * 16 + q];
            acc[0] = fmaf(bflo(p.x), scale, acc[0]);
            acc[1] = fmaf(bfhi(p.x), scale, acc[1]);
            acc[2] = fmaf(bflo(p.y), scale, acc[2]);
            acc[3] = fmaf(bfhi(p.y), scale, acc[3]);
            acc[4] = fmaf(bflo(p.z), scale, acc[4]);
            acc[5] = fmaf(bfhi(p.z), scale, acc[5]);
            acc[6] = fmaf(bflo(p.w), scale, acc[6]);
            acc[7] = fmaf(bfhi(p.w), scale, acc[7]);
        }
#pragma unroll
        for (int d = 16; d < 64; d <<= 1) {
#pragma unroll
            for (int i = 0; i < 8; ++i) acc[i] += __shfl_xor(acc[i], d);
        }
        if (g == 0) {
            uint4 p = hbq[(size_t)v * 16 + q];     // self term (bf16 row)
            acc[0] += bflo(p.x); acc[1] += bfhi(p.x);
            acc[2] += bflo(p.y); acc[3] += bfhi(p.y);
            acc[4] += bflo(p.z); acc[5] += bfhi(p.z);
            acc[6] += bflo(p.w); acc[7] += bfhi(p.w);
            float4 a0 = {acc[0], acc[1], acc[2], acc[3]};
            float4 a1 = {acc[4], acc[5], acc[6], acc[7]};
            *(float4*)&sZ[wv * 2 + n][q * 8]     = a0;
            *(float4*)&sZ[wv * 2 + n][q * 8 + 4] = a1;
        }
    }
    __syncthreads();

    // ---- GEMM phase: 512 threads, col = tid&127, 4 groups x 4 rows ----
    const int col = tid & 127;
    const int gg  = tid >> 7;   // 0..3
    float acc2[4] = {0.f, 0.f, 0.f, 0.f};
#pragma unroll 2
    for (int k = 0; k < 128; k += 4) {
        float w0 = W[(k + 0) * 128 + col];
        float w1 = W[(k + 1) * 128 + col];
        float w2 = W[(k + 2) * 128 + col];
        float w3 = W[(k + 3) * 128 + col];
#pragma unroll
        for (int r = 0; r < 4; ++r) {
            float4 z = *(const float4*)&sZ[gg * 4 + r][k];  // broadcast
            acc2[r] = fmaf(z.x, w0, acc2[r]);
            acc2[r] = fmaf(z.y, w1, acc2[r]);
            acc2[r] = fmaf(z.z, w2, acc2[r]);
            acc2[r] = fmaf(z.w, w3, acc2[r]);
        }
    }
    const float b = bias[col];
#pragma unroll
    for (int r = 0; r < 4; ++r) {
        const int vv = tile0 + gg * 4 + r;
        float y = fmaxf(acc2[r] + b, 0.f);
        __hip_bfloat16 bv = __float2bfloat16(y);
        hb_out[(size_t)vv * FEATS + col] = *(const ushort*)&bv;
    }
}

// ---------------- layer 4a: y = h @ W2 (128->64), bf16 out, no bias --------

__global__ __launch_bounds__(256) void gemm64(const ushort* __restrict__ hb,
                                              const float* __restrict__ W,
                                              ushort* __restrict__ yb) {
    __shared__ float sZ[16][132];
    const int node0 = blockIdx.x * 16;
    const int tid = threadIdx.x;
    const uint* hrow = (const uint*)(hb + (size_t)node0 * 128);
    for (int i = tid; i < 16 * 64; i += 256) {   // 1024 uints = 16 rows x 128 bf16
        uint p = hrow[i];
        int row = i >> 6, c2 = (i & 63) * 2;
        sZ[row][c2] = bflo(p);
        sZ[row][c2 + 1] = bfhi(p);
    }
    __syncthreads();
    const int col = tid & 63;
    const int g = tid >> 6;   // 4 groups x 4 rows
    float acc[4] = {0.f, 0.f, 0.f, 0.f};
#pragma unroll 2
    for (int k = 0; k < 128; k += 4) {
        float w0 = W[(k + 0) * 64 + col];
        float w1 = W[(k + 1) * 64 + col];
        float w2 = W[(k + 2) * 64 + col];
        float w3 = W[(k + 3) * 64 + col];
#pragma unroll
        for (int r = 0; r < 4; ++r) {
            float4 z = *(const float4*)&sZ[g * 4 + r][k];  // broadcast
            acc[r] = fmaf(z.x, w0, acc[r]);
            acc[r] = fmaf(z.y, w1, acc[r]);
            acc[r] = fmaf(z.z, w2, acc[r]);
            acc[r] = fmaf(z.w, w3, acc[r]);
        }
    }
#pragma unroll
    for (int r = 0; r < 4; ++r) {
        __hip_bfloat16 bv = __float2bfloat16(acc[r]);
        yb[(size_t)(node0 + g * 4 + r) * 64 + col] = *(const ushort*)&bv;
    }
}

// ---------------- layer 4b: out[v] = y[v] + sum_u y[u] + b2 (64-wide) ------

__global__ __launch_bounds__(256) void agg64(const ushort* __restrict__ yb,
                                             const int* __restrict__ cnts,
                                             const ushort* __restrict__ ell,
                                             const float* __restrict__ bias,
                                             float* __restrict__ out) {
    const int v = blockIdx.x * 4 + (threadIdx.x >> 6);
    const int lane = threadIdx.x & 63;
    const int g = lane >> 3;   // 8 edge groups per iter
    const int q = lane & 7;    // 16B chunk within 128B row
    int cnt = cnts[v];
    if (cnt > CAP) cnt = CAP;
    const ushort* __restrict__ row = ell + (size_t)v * CAP;
    const uint4* __restrict__ ybq = (const uint4*)yb;
    float acc[8];
#pragma unroll
    for (int i = 0; i < 8; ++i) acc[i] = 0.f;
#pragma unroll 2
    for (int j = 0; j < cnt; j += 8) {
        uint4 iv = *(const uint4*)(row + j);   // 8 indices, broadcast load
        uint a = (g & 2) ? iv.y : iv.x;
        uint b = (g & 2) ? iv.w : iv.z;
        uint word = (g & 4) ? b : a;
        uint u = (g & 1) ? (word >> 16) : (word & 0xffffu);
        float scale = (j + g < cnt) ? 1.0f : 0.0f;
        if (u > N_NODES - 1) u = N_NODES - 1;
        uint4 p = ybq[u * 8 + q];
        acc[0] = fmaf(bflo(p.x), scale, acc[0]);
        acc[1] = fmaf(bfhi(p.x), scale, acc[1]);
        acc[2] = fmaf(bflo(p.y), scale, acc[2]);
        acc[3] = fmaf(bfhi(p.y), scale, acc[3]);
        acc[4] = fmaf(bflo(p.z), scale, acc[4]);
        acc[5] = fmaf(bfhi(p.z), scale, acc[5]);
        acc[6] = fmaf(bflo(p.w), scale, acc[6]);
        acc[7] = fmaf(bfhi(p.w), scale, acc[7]);
    }
#pragma unroll
    for (int d = 8; d < 64; d <<= 1) {
#pragma unroll
        for (int i = 0; i < 8; ++i) acc[i] += __shfl_xor(acc[i], d);
    }
    if (g == 0) {
        uint4 p = ybq[(size_t)v * 8 + q];   // self term y[v] (bf16)
        const float4* br = (const float4*)bias;
        float4 b0 = br[q * 2], b1 = br[q * 2 + 1];
        float4 o0, o1;
        o0.x = acc[0] + bflo(p.x) + b0.x; o0.y = acc[1] + bfhi(p.x) + b0.y;
        o0.z = acc[2] + bflo(p.y) + b0.z; o0.w = acc[3] + bfhi(p.y) + b0.w;
        o1.x = acc[4] + bflo(p.z) + b1.x; o1.y = acc[5] + bfhi(p.z) + b1.y;
        o1.z = acc[6] + bflo(p.w) + b1.z; o1.w = acc[7] + bfhi(p.w) + b1.w;
        float4* outr = (float4*)(out + (size_t)v * 64);
        outr[q * 2]     = o0;
        outr[q * 2 + 1] = o1;
    }
}

// ---------------- launch ----------------

extern "C" void kernel_launch(void* const* d_in, const int* in_sizes, int n_in,
                              void* d_out, int out_size, void* d_ws, size_t ws_size,
                              hipStream_t stream) {
    const float* features = (const float*)d_in[0];
    const int*   src      = (const int*)d_in[1];
    const int*   dst      = (const int*)d_in[2];
    const float* W1 = (const float*)d_in[3];
    const float* b1 = (const float*)d_in[4];
    const float* W3 = (const float*)d_in[5];
    const float* b3 = (const float*)d_in[6];
    const float* W4 = (const float*)d_in[7];
    const float* b4 = (const float*)d_in[8];
    const float* W2 = (const float*)d_in[9];
    const float* b2 = (const float*)d_in[10];
    float* out = (float*)d_out;

    int*    cnts     = (int*)d_ws;                         // 10240 ints
    ushort* goffs    = (ushort*)(cnts + 10240);            // NPB*OSTR ushorts
    uint*   bucketed = (uint*)(goffs + 50240);             // NPB*ECHUNK uints (2.56 MB)
    ushort* ell      = (ushort*)(bucketed + (size_t)NPB * ECHUNK); // 3.84 MB
    ushort* hb0      = ell + (size_t)N_NODES * CAP;        // 10000*128 bf16
    ushort* hb1      = hb0 + (size_t)N_NODES * FEATS;      // 10000*128 bf16
    ushort* yb64     = hb1 + (size_t)N_NODES * FEATS;      // 10000*64 bf16

    bin_pack<<<NPB, 256, 0, stream>>>(src, dst, bucketed, goffs, features, hb0);
    build_ell<<<NBUCK, 256, 0, stream>>>(bucketed, goffs, ell, cnts);

    const int fblocks = N_NODES / TILE;  // 625

    fused_kernel<<<fblocks, 512, 0, stream>>>(hb0, W1, b1, cnts, ell, hb1);
    fused_kernel<<<fblocks, 512, 0, stream>>>(hb1, W3, b3, cnts, ell, hb0);
    fused_kernel<<<fblocks, 512, 0, stream>>>(hb0, W4, b4, cnts, ell, hb1);
    // Layer 4: y = h3@W2 (64-wide), then out = y[v] + sum y[u] + b2
    gemm64<<<N_NODES / 16, 256, 0, stream>>>(hb1, W2, yb64);
    agg64<<<N_NODES / 4, 256, 0, stream>>>(yb64, cnts, ell, b2, out);
}

// Round 15
// 114.303 us; speedup vs baseline: 1.2981x; 1.0851x over previous
//
#include <hip/hip_runtime.h>
#include <hip/hip_bf16.h>

#define N_NODES 10000
#define N_EDGES 640000
#define FEATS   128
#define CAP     192    // ELL slots/node; degree ~ Poisson(64), P(>192) ~ 0
#define NBUCK   157    // buckets of 64 dst-nodes
#define ECHUNK  2048   // edges per phase-1 block (private region size)
#define NPB     313    // phase-1 blocks = ceil(640000/2048)
#define OSTR    160    // goffs row stride (ushorts)
#define TILE    8      // nodes per fused block (4 waves x 2 nodes) — best measured

__device__ __forceinline__ float bflo(uint p) { return __uint_as_float(p << 16); }
__device__ __forceinline__ float bfhi(uint p) { return __uint_as_float(p & 0xffff0000u); }

// ---- phase 1: per-block private bucket-sort; ALL writes streaming ---------
// (+ grid-stride f32->bf16 feature conversion tail). No NT loads anywhere
// (R13: NT on the index chain cost +25%).

__global__ __launch_bounds__(256) void bin_pack(const int* __restrict__ src,
                                                const int* __restrict__ dst,
                                                uint* __restrict__ bucketed,
                                                ushort* __restrict__ goffs,
                                                const float* __restrict__ features,
                                                ushort* __restrict__ hb0) {
    __shared__ int hist[NBUCK];
    __shared__ int offs[NBUCK + 1];
    __shared__ int scan[256];
    __shared__ uint staging[ECHUNK];  // 8 KB
    const int tid = threadIdx.x;
    const int b = blockIdx.x;
    const int e0 = b * ECHUNK;
    for (int i = tid; i < NBUCK; i += 256) hist[i] = 0;
    __syncthreads();
    int dreg[8];
#pragma unroll
    for (int i = 0; i < 8; ++i) {
        int e = e0 + tid + i * 256;
        dreg[i] = (e < N_EDGES) ? dst[e] : -1;
        if (dreg[i] >= 0) atomicAdd(&hist[dreg[i] >> 6], 1);
    }
    __syncthreads();
    int val = (tid < NBUCK) ? hist[tid] : 0;
    scan[tid] = val;
    __syncthreads();
    for (int off = 1; off < 256; off <<= 1) {
        int t = (tid >= off) ? scan[tid - off] : 0;
        __syncthreads();
        scan[tid] += t;
        __syncthreads();
    }
    if (tid < NBUCK) offs[tid] = scan[tid] - val;   // exclusive
    if (tid == 0) offs[NBUCK] = scan[NBUCK - 1];    // total real edges
    for (int i = tid; i < NBUCK; i += 256) hist[i] = 0;
    __syncthreads();
    if (tid <= NBUCK) goffs[b * OSTR + tid] = (ushort)offs[tid];
#pragma unroll
    for (int i = 0; i < 8; ++i) {
        int e = e0 + tid + i * 256;
        if (dreg[i] >= 0) {
            int s = src[e];
            int bk = dreg[i] >> 6;
            int slot = offs[bk] + atomicAdd(&hist[bk], 1);
            staging[slot] = ((uint)s << 6) | (uint)(dreg[i] & 63);
        }
    }
    __syncthreads();
    uint4* gu = (uint4*)(bucketed + (size_t)b * ECHUNK);
    const uint4* lu = (const uint4*)staging;
#pragma unroll
    for (int i = 0; i < ECHUNK / 4 / 256; ++i)
        gu[tid + i * 256] = lu[tid + i * 256];

    // ---- f2b tail: features f32 -> bf16 table (grid-stride) ----
    const int n4 = N_NODES * FEATS / 4;
    for (int i = b * 256 + tid; i < n4; i += NPB * 256) {
        float4 f = ((const float4*)features)[i];
        __hip_bfloat16 b0 = __float2bfloat16(f.x);
        __hip_bfloat16 b1 = __float2bfloat16(f.y);
        __hip_bfloat16 b2 = __float2bfloat16(f.z);
        __hip_bfloat16 b3 = __float2bfloat16(f.w);
        ushort4 o;
        o.x = *(const ushort*)&b0; o.y = *(const ushort*)&b1;
        o.z = *(const ushort*)&b2; o.w = *(const ushort*)&b3;
        ((ushort4*)hb0)[i] = o;
    }
}

// ---- phase 2: per-bucket ELL in LDS; 256 INDEPENDENT span-walkers ---------

__global__ __launch_bounds__(256) void build_ell(const uint* __restrict__ bucketed,
                                                 const ushort* __restrict__ goffs,
                                                 ushort* __restrict__ ell,
                                                 int* __restrict__ cnts) {
    __shared__ ushort lell[64 * CAP];  // 24 KB
    __shared__ int lcur[64];
    const int tid = threadIdx.x;
    const int bk = blockIdx.x;
    if (tid < 64) lcur[tid] = 0;
    __syncthreads();
    for (int b = tid; b < NPB; b += 256) {
        int off0 = goffs[b * OSTR + bk];
        int off1 = goffs[b * OSTR + bk + 1];
        const uint* p0 = bucketed + (size_t)b * ECHUNK;
        for (int i = off0; i < off1; ++i) {
            uint p = p0[i];
            int v = p & 63;
            int slot = atomicAdd(&lcur[v], 1);
            if (slot < CAP) lell[v * CAP + slot] = (ushort)(p >> 6);
        }
    }
    __syncthreads();
    const int node0 = bk * 64;
    int nn = N_NODES - node0;
    if (nn > 64) nn = 64;
    const uint4* lu = (const uint4*)lell;
    uint4* gu = (uint4*)(ell + (size_t)node0 * CAP);
    const int nq = nn * (CAP / 8);
    for (int i = tid; i < nq; i += 256) gu[i] = lu[i];
    for (int v = tid; v < nn; v += 256) {
        int c = lcur[v];
        cnts[node0 + v] = (c > CAP) ? CAP : c;
    }
}

// ---- gather helper: z[tile] into sZ (TILE=8, 4 waves x 2 nodes) -----------

__device__ __forceinline__ void gather_tile(const uint4* __restrict__ hbq,
                                            const int* __restrict__ cnts,
                                            const ushort* __restrict__ ell,
                                            int tile0, int tid,
                                            float (*sZ)[132]) {
    const int lane = tid & 63;
    const int wv = tid >> 6;
    const int g = lane >> 4;   // edge group (4 edges/iter)
    const int q = lane & 15;   // 16B chunk within 256B row
#pragma unroll
    for (int n = 0; n < 2; ++n) {
        const int v = tile0 + wv * 2 + n;
        int cnt = cnts[v];
        if (cnt > CAP) cnt = CAP;
        const ushort* __restrict__ row = ell + (size_t)v * CAP;
        float acc[8];
#pragma unroll
        for (int i = 0; i < 8; ++i) acc[i] = 0.f;
#pragma unroll 2
        for (int j = 0; j < cnt; j += 4) {
            uint2 iv = *(const uint2*)(row + j);   // broadcast index load (L1-hot)
            uint word = (g & 2) ? iv.y : iv.x;
            uint u = (g & 1) ? (word >> 16) : (word & 0xffffu);
            float scale = (j + g < cnt) ? 1.0f : 0.0f;
            if (u > N_NODES - 1) u = N_NODES - 1;  // clamp garbage tail index
            uint4 p = hbq[u * 16 + q];
            acc[0] = fmaf(bflo(p.x), scale, acc[0]);
            acc[1] = fmaf(bfhi(p.x), scale, acc[1]);
            acc[2] = fmaf(bflo(p.y), scale, acc[2]);
            acc[3] = fmaf(bfhi(p.y), scale, acc[3]);
            acc[4] = fmaf(bflo(p.z), scale, acc[4]);
            acc[5] = fmaf(bfhi(p.z), scale, acc[5]);
            acc[6] = fmaf(bflo(p.w), scale, acc[6]);
            acc[7] = fmaf(bfhi(p.w), scale, acc[7]);
        }
#pragma unroll
        for (int d = 16; d < 64; d <<= 1) {
#pragma unroll
            for (int i = 0; i < 8; ++i) acc[i] += __shfl_xor(acc[i], d);
        }
        if (g == 0) {
            uint4 p = hbq[(size_t)(tile0 + wv * 2 + n) * 16 + q];  // self term
            acc[0] += bflo(p.x); acc[1] += bfhi(p.x);
            acc[2] += bflo(p.y); acc[3] += bfhi(p.y);
            acc[4] += bflo(p.z); acc[5] += bfhi(p.z);
            acc[6] += bflo(p.w); acc[7] += bfhi(p.w);
            float4 a0 = {acc[0], acc[1], acc[2], acc[3]};
            float4 a1 = {acc[4], acc[5], acc[6], acc[7]};
            *(float4*)&sZ[wv * 2 + n][q * 8]     = a0;
            *(float4*)&sZ[wv * 2 + n][q * 8 + 4] = a1;
        }
    }
}

// ---------------- fused hidden layer (1,2): out = relu(z@W + b) bf16 -------

__global__ __launch_bounds__(256) void fused_kernel(const ushort* __restrict__ hb,
                                                    const float* __restrict__ W,
                                                    const float* __restrict__ bias,
                                                    const int* __restrict__ cnts,
                                                    const ushort* __restrict__ ell,
                                                    ushort* __restrict__ hb_out) {
    __shared__ float sZ[TILE][132];
    const int tile0 = blockIdx.x * TILE;
    const int tid = threadIdx.x;
    gather_tile((const uint4*)hb, cnts, ell, tile0, tid, sZ);
    __syncthreads();

    const int col = tid & 127;
    const int gg  = tid >> 7;   // 0..1, 4 rows each
    float acc2[4] = {0.f, 0.f, 0.f, 0.f};
#pragma unroll 2
    for (int k = 0; k < 128; k += 4) {
        float w0 = W[(k + 0) * 128 + col];
        float w1 = W[(k + 1) * 128 + col];
        float w2 = W[(k + 2) * 128 + col];
        float w3 = W[(k + 3) * 128 + col];
#pragma unroll
        for (int r = 0; r < 4; ++r) {
            float4 z = *(const float4*)&sZ[gg * 4 + r][k];  // broadcast
            acc2[r] = fmaf(z.x, w0, acc2[r]);
            acc2[r] = fmaf(z.y, w1, acc2[r]);
            acc2[r] = fmaf(z.z, w2, acc2[r]);
            acc2[r] = fmaf(z.w, w3, acc2[r]);
        }
    }
    const float b = bias[col];
#pragma unroll
    for (int r = 0; r < 4; ++r) {
        const int vv = tile0 + gg * 4 + r;
        float y = fmaxf(acc2[r] + b, 0.f);
        __hip_bfloat16 bv = __float2bfloat16(y);
        hb_out[(size_t)vv * FEATS + col] = *(const ushort*)&bv;
    }
}

// ---------------- fused layer 3 + layer-4 GEMM --------------------------
// h3 = relu(z@W4+b4) stays in LDS (never hits global); y = h3@W2 -> bf16.
// Eliminates the separate gemm64 kernel + h3 write/read round-trip.

__global__ __launch_bounds__(256) void fused3_kernel(const ushort* __restrict__ hb,
                                                     const float* __restrict__ W4,
                                                     const float* __restrict__ b4,
                                                     const float* __restrict__ W2,
                                                     const int* __restrict__ cnts,
                                                     const ushort* __restrict__ ell,
                                                     ushort* __restrict__ yb64) {
    __shared__ float sZ[TILE][132];
    __shared__ float sH[TILE][132];
    const int tile0 = blockIdx.x * TILE;
    const int tid = threadIdx.x;
    gather_tile((const uint4*)hb, cnts, ell, tile0, tid, sZ);
    __syncthreads();

    // GEMM A: h3 = relu(z @ W4 + b4) -> sH (f32, LDS only)
    {
        const int col = tid & 127;
        const int gg  = tid >> 7;   // 0..1, 4 rows each
        float acc2[4] = {0.f, 0.f, 0.f, 0.f};
#pragma unroll 2
        for (int k = 0; k < 128; k += 4) {
            float w0 = W4[(k + 0) * 128 + col];
            float w1 = W4[(k + 1) * 128 + col];
            float w2 = W4[(k + 2) * 128 + col];
            float w3 = W4[(k + 3) * 128 + col];
#pragma unroll
            for (int r = 0; r < 4; ++r) {
                float4 z = *(const float4*)&sZ[gg * 4 + r][k];  // broadcast
                acc2[r] = fmaf(z.x, w0, acc2[r]);
                acc2[r] = fmaf(z.y, w1, acc2[r]);
                acc2[r] = fmaf(z.z, w2, acc2[r]);
                acc2[r] = fmaf(z.w, w3, acc2[r]);
            }
        }
        const float b = b4[col];
#pragma unroll
        for (int r = 0; r < 4; ++r)
            sH[gg * 4 + r][col] = fmaxf(acc2[r] + b, 0.f);
    }
    __syncthreads();

    // GEMM B: y = h3 @ W2 (128->64) -> yb64 bf16 (no bias; b2 added in agg64)
    {
        const int col = tid & 63;
        const int gg  = tid >> 6;   // 0..3, 2 rows each
        float acc3[2] = {0.f, 0.f};
#pragma unroll 2
        for (int k = 0; k < 128; k += 4) {
            float w0 = W2[(k + 0) * 64 + col];
            float w1 = W2[(k + 1) * 64 + col];
            float w2 = W2[(k + 2) * 64 + col];
            float w3 = W2[(k + 3) * 64 + col];
#pragma unroll
            for (int r = 0; r < 2; ++r) {
                float4 z = *(const float4*)&sH[gg * 2 + r][k];  // broadcast
                acc3[r] = fmaf(z.x, w0, acc3[r]);
                acc3[r] = fmaf(z.y, w1, acc3[r]);
                acc3[r] = fmaf(z.z, w2, acc3[r]);
                acc3[r] = fmaf(z.w, w3, acc3[r]);
            }
        }
#pragma unroll
        for (int r = 0; r < 2; ++r) {
            const int vv = tile0 + gg * 2 + r;
            __hip_bfloat16 bv = __float2bfloat16(acc3[r]);
            yb64[(size_t)vv * 64 + col] = *(const ushort*)&bv;
        }
    }
}

// ---------------- layer 4b: out[v] = y[v] + sum_u y[u] + b2 (64-wide) ------

__global__ __launch_bounds__(256) void agg64(const ushort* __restrict__ yb,
                                             const int* __restrict__ cnts,
                                             const ushort* __restrict__ ell,
                                             const float* __restrict__ bias,
                                             float* __restrict__ out) {
    const int v = blockIdx.x * 4 + (threadIdx.x >> 6);
    const int lane = threadIdx.x & 63;
    const int g = lane >> 3;   // 8 edge groups per iter
    const int q = lane & 7;    // 16B chunk within 128B row
    int cnt = cnts[v];
    if (cnt > CAP) cnt = CAP;
    const ushort* __restrict__ row = ell + (size_t)v * CAP;
    const uint4* __restrict__ ybq = (const uint4*)yb;
    float acc[8];
#pragma unroll
    for (int i = 0; i < 8; ++i) acc[i] = 0.f;
#pragma unroll 2
    for (int j = 0; j < cnt; j += 8) {
        uint4 iv = *(const uint4*)(row + j);   // 8 indices, broadcast load
        uint a = (g & 2) ? iv.y : iv.x;
        uint b = (g & 2) ? iv.w : iv.z;
        uint word = (g & 4) ? b : a;
        uint u = (g & 1) ? (word >> 16) : (word & 0xffffu);
        float scale = (j + g < cnt) ? 1.0f : 0.0f;
        if (u > N_NODES - 1) u = N_NODES - 1;
        uint4 p = ybq[u * 8 + q];
        acc[0] = fmaf(bflo(p.x), scale, acc[0]);
        acc[1] = fmaf(bfhi(p.x), scale, acc[1]);
        acc[2] = fmaf(bflo(p.y), scale, acc[2]);
        acc[3] = fmaf(bfhi(p.y), scale, acc[3]);
        acc[4] = fmaf(bflo(p.z), scale, acc[4]);
        acc[5] = fmaf(bfhi(p.z), scale, acc[5]);
        acc[6] = fmaf(bflo(p.w), scale, acc[6]);
        acc[7] = fmaf(bfhi(p.w), scale, acc[7]);
    }
#pragma unroll
    for (int d = 8; d < 64; d <<= 1) {
#pragma unroll
        for (int i = 0; i < 8; ++i) acc[i] += __shfl_xor(acc[i], d);
    }
    if (g == 0) {
        uint4 p = ybq[(size_t)v * 8 + q];   // self term y[v] (bf16)
        const float4* br = (const float4*)bias;
        float4 b0 = br[q * 2], b1 = br[q * 2 + 1];
        float4 o0, o1;
        o0.x = acc[0] + bflo(p.x) + b0.x; o0.y = acc[1] + bfhi(p.x) + b0.y;
        o0.z = acc[2] + bflo(p.y) + b0.z; o0.w = acc[3] + bfhi(p.y) + b0.w;
        o1.x = acc[4] + bflo(p.z) + b1.x; o1.y = acc[5] + bfhi(p.z) + b1.y;
        o1.z = acc[6] + bflo(p.w) + b1.z; o1.w = acc[7] + bfhi(p.w) + b1.w;
        float4* outr = (float4*)(out + (size_t)v * 64);
        outr[q * 2]     = o0;
        outr[q * 2 + 1] = o1;
    }
}

// ---------------- launch ----------------

extern "C" void kernel_launch(void* const* d_in, const int* in_sizes, int n_in,
                              void* d_out, int out_size, void* d_ws, size_t ws_size,
                              hipStream_t stream) {
    const float* features = (const float*)d_in[0];
    const int*   src      = (const int*)d_in[1];
    const int*   dst      = (const int*)d_in[2];
    const float* W1 = (const float*)d_in[3];
    const float* b1 = (const float*)d_in[4];
    const float* W3 = (const float*)d_in[5];
    const float* b3 = (const float*)d_in[6];
    const float* W4 = (const float*)d_in[7];
    const float* b4 = (const float*)d_in[8];
    const float* W2 = (const float*)d_in[9];
    const float* b2 = (const float*)d_in[10];
    float* out = (float*)d_out;

    int*    cnts     = (int*)d_ws;                         // 10240 ints
    ushort* goffs    = (ushort*)(cnts + 10240);            // NPB*OSTR ushorts
    uint*   bucketed = (uint*)(goffs + 50240);             // NPB*ECHUNK uints (2.56 MB)
    ushort* ell      = (ushort*)(bucketed + (size_t)NPB * ECHUNK); // 3.84 MB
    ushort* hb0      = ell + (size_t)N_NODES * CAP;        // 10000*128 bf16
    ushort* hb1      = hb0 + (size_t)N_NODES * FEATS;      // 10000*128 bf16
    ushort* yb64     = hb1 + (size_t)N_NODES * FEATS;      // 10000*64 bf16

    bin_pack<<<NPB, 256, 0, stream>>>(src, dst, bucketed, goffs, features, hb0);
    build_ell<<<NBUCK, 256, 0, stream>>>(bucketed, goffs, ell, cnts);

    const int fblocks = N_NODES / TILE;  // 1250

    fused_kernel<<<fblocks, 256, 0, stream>>>(hb0, W1, b1, cnts, ell, hb1);
    fused_kernel<<<fblocks, 256, 0, stream>>>(hb1, W3, b3, cnts, ell, hb0);
    // Layer 3 + layer-4 GEMM fused: h3 stays in LDS, y = h3@W2 -> yb64
    fused3_kernel<<<fblocks, 256, 0, stream>>>(hb0, W4, b4, W2, cnts, ell, yb64);
    // Layer 4 aggregate: out = y[v] + sum y[u] + b2
    agg64<<<N_NODES / 4, 256, 0, stream>>>(yb64, cnts, ell, b2, out);
}